// Round 2
// baseline (491.982 us; speedup 1.0000x reference)
//
#include <hip/hip_runtime.h>

// out[B=16384, ONUM=512] = x[B, INUM=4096] @ wB[ONUM, INUM]^T, wB = (u < weight)
// v3: counted-vmcnt pipeline (no vmcnt(0) drain in main loop), prefetch depth 2,
// BM=64 x BN=512 tile so x (the L3-resident 256MB operand) is staged exactly once.
// 256 blocks (1/CU) x 1024 threads (16 waves, 4/SIMD). LDS 138 KB: A dbuf + B 4-buf.

#define M_DIM 16384
#define N_DIM 512
#define K_DIM 4096
#define BM 64
#define BK 32
#define NT (K_DIM / BK)          // 128
#define THREADS 1024

using bf16x8 = __attribute__((ext_vector_type(8))) short;
using f32x4  = __attribute__((ext_vector_type(4))) float;

typedef __attribute__((address_space(1))) const void glb_cv;
typedef __attribute__((address_space(3))) void lds_v;

__device__ __forceinline__ unsigned short f2bf(float f) {
    union { float f; unsigned int u; } v;
    v.f = f;
    unsigned int r = v.u + 0x7FFFu + ((v.u >> 16) & 1u);   // RNE
    return (unsigned short)(r >> 16);
}

// ---------------- binarize: wB[o,k] = (u < weight) ? 1.0bf16 : 0 ----------------
__global__ __launch_bounds__(256) void binarize_kernel(const float* __restrict__ w,
                                                       const float* __restrict__ u,
                                                       unsigned short* __restrict__ wb) {
    int i = (blockIdx.x * 256 + threadIdx.x) * 4;
    float4 wv = *(const float4*)(w + i);
    float4 uv = *(const float4*)(u + i);
    ushort4 o;
    o.x = (uv.x < wv.x) ? 0x3F80u : 0u;
    o.y = (uv.y < wv.y) ? 0x3F80u : 0u;
    o.z = (uv.z < wv.z) ? 0x3F80u : 0u;
    o.w = (uv.w < wv.w) ? 0x3F80u : 0u;
    *(ushort4*)(wb + i) = o;
}

// ---------------- GEMM ----------------
__global__ __launch_bounds__(THREADS, 4) void gemm_bin_kernel(const float* __restrict__ x,
                                                              const unsigned short* __restrict__ wb,
                                                              float* __restrict__ out) {
    // A: 2 buffers, padded rows (stride 80 B) — reg-staged ds_write.
    // B: 4 buffers, linear dest for global_load_lds; XOR-swizzled CONTENT:
    //    LDS chunk (row, kc) holds global chunk (row, kc ^ ((row>>1)&3)).
    __shared__ __attribute__((aligned(16))) unsigned short As[2][BM][40];
    __shared__ __attribute__((aligned(16))) unsigned short Bs[4][N_DIM][BK];

    const int t    = threadIdx.x;
    const int lane = t & 63;
    const int wave = t >> 6;                  // 0..15
    const int bm   = blockIdx.x;              // 256 blocks = M tiles

    const int wm  = (wave >> 3) * 32;         // 2 m-groups of 32 rows
    const int wn  = (wave & 7) * 64;          // 8 n-groups of 64 cols
    const int khi = lane >> 4;                // 0..3
    const int l15 = lane & 15;

    f32x4 acc[2][4] = {};

    const float* xg = x + (size_t)(bm * BM) * K_DIM;
    // A staging: every thread loads/stores one float2 -> UNIFORM vmem count/wave
    const int ar = t >> 4;                    // 0..63
    const int ac = (t & 15) * 2;              // 0..30

    float2 ra, rb_;

#define LOADA(reg, k0) reg = *(const float2*)(xg + (size_t)ar * K_DIM + (k0) + ac)

#define STOREA(b, reg) { ushort2 h; h.x = f2bf((reg).x); h.y = f2bf((reg).y);   \
                         *(ushort2*)(&As[b][ar][ac]) = h; }

    // B tile: 512x32 bf16 = 32 KB = 2048 x 16B chunks; 2 gll/thread (uniform).
    // Pre-swizzled SOURCE (rule 21): fetch global chunk (rbw, kc ^ ((rbw>>1)&3)).
#define GLLB(b, k0)                                                              \
    _Pragma("unroll")                                                            \
    for (int c = 0; c < 2; ++c) {                                                \
        int e   = c * THREADS + t;                                               \
        int rbw = e >> 2;                                                        \
        int kc  = (e & 3) ^ ((rbw >> 1) & 3);                                    \
        const unsigned short* gsrc = wb + (size_t)rbw * K_DIM + (k0) + kc * 8;   \
        unsigned short* ldst = (unsigned short*)&Bs[b][0][0] + (size_t)e * 8;    \
        __builtin_amdgcn_global_load_lds((glb_cv*)(const void*)gsrc,             \
                                         (lds_v*)(void*)ldst, 16, 0, 0);         \
    }

#define COMPUTE(ab, bb) {                                                        \
    bf16x8 af[2], bfr[4];                                                        \
    _Pragma("unroll") for (int i = 0; i < 2; ++i)                                \
        af[i] = *(const bf16x8*)(&As[ab][wm + i * 16 + l15][khi * 8]);           \
    _Pragma("unroll") for (int j = 0; j < 4; ++j) {                              \
        int row = wn + j * 16 + l15;                                             \
        int kc  = khi ^ ((row >> 1) & 3);                                        \
        bfr[j] = *(const bf16x8*)(&Bs[bb][row][kc * 8]);                         \
    }                                                                            \
    _Pragma("unroll") for (int i = 0; i < 2; ++i)                                \
        _Pragma("unroll") for (int j = 0; j < 4; ++j)                            \
            acc[i][j] = __builtin_amdgcn_mfma_f32_16x16x32_bf16(af[i], bfr[j],   \
                                                                acc[i][j], 0, 0, 0); \
}

    // Counted-vmcnt barrier: keeps next-next tile's 3 vmem ops in flight.
#define BAR3 { asm volatile("s_waitcnt vmcnt(3) lgkmcnt(0)" ::: "memory");       \
               __builtin_amdgcn_s_barrier();                                     \
               __builtin_amdgcn_sched_barrier(0); }
#define BAR0 { asm volatile("s_waitcnt vmcnt(0) lgkmcnt(0)" ::: "memory");       \
               __builtin_amdgcn_s_barrier();                                     \
               __builtin_amdgcn_sched_barrier(0); }

    // ---- prologue: B tiles 0,1 in flight; A tile 0 -> LDS; A tile 1 -> regs ----
    GLLB(0, 0);
    GLLB(1, BK);
    LOADA(ra, 0);
    STOREA(0, ra);            // implicit wait on ra retires B(0),B(1) too
    LOADA(rb_, BK);           // stays in flight across the barrier
    asm volatile("s_waitcnt lgkmcnt(0)" ::: "memory");
    __builtin_amdgcn_s_barrier();
    __builtin_amdgcn_sched_barrier(0);

    // ---- main loop: step t computes buf[t], issues tile t+2, stores A(t+1) ----
    // Invariant at BAR3: outstanding = {B(t+2) x2, A(t+2) x1}; B(t+1),A(t+1) retired.
    int kpf = 2 * BK;
    for (int t4 = 0; t4 < NT - 4; t4 += 4) {
        GLLB(2, kpf); LOADA(ra,  kpf); COMPUTE(0, 0); STOREA(1, rb_); BAR3; kpf += BK;
        GLLB(3, kpf); LOADA(rb_, kpf); COMPUTE(1, 1); STOREA(0, ra);  BAR3; kpf += BK;
        GLLB(0, kpf); LOADA(ra,  kpf); COMPUTE(0, 2); STOREA(1, rb_); BAR3; kpf += BK;
        GLLB(1, kpf); LOADA(rb_, kpf); COMPUTE(1, 3); STOREA(0, ra);  BAR3; kpf += BK;
    }
    // t = 124, 125: full bodies
    GLLB(2, kpf); LOADA(ra,  kpf); COMPUTE(0, 0); STOREA(1, rb_); BAR3; kpf += BK;
    GLLB(3, kpf); LOADA(rb_, kpf); COMPUTE(1, 1); STOREA(0, ra);  BAR3;
    // t = 126: no prefetch left; drain
    COMPUTE(0, 2); STOREA(1, rb_); BAR0;
    // t = 127: compute only
    COMPUTE(1, 3);

    // ---- epilogue: C/D layout col=lane&15, row=(lane>>4)*4+reg ----
    const int col0 = wn + l15;
    const int row0 = bm * BM + wm + khi * 4;
#pragma unroll
    for (int i = 0; i < 2; ++i)
#pragma unroll
        for (int j = 0; j < 4; ++j)
#pragma unroll
            for (int r = 0; r < 4; ++r)
                out[(size_t)(row0 + i * 16 + r) * N_DIM + (col0 + j * 16)] = acc[i][j][r];
}

extern "C" void kernel_launch(void* const* d_in, const int* in_sizes, int n_in,
                              void* d_out, int out_size, void* d_ws, size_t ws_size,
                              hipStream_t stream) {
    const float* x = (const float*)d_in[0];
    const float* w = (const float*)d_in[1];
    const float* u = (const float*)d_in[2];
    float* out = (float*)d_out;
    unsigned short* wb = (unsigned short*)d_ws;   // 512*4096*2 = 4 MB

    binarize_kernel<<<dim3(N_DIM * K_DIM / 4 / 256), dim3(256), 0, stream>>>(w, u, wb);

    gemm_bin_kernel<<<dim3(M_DIM / BM), dim3(THREADS), 0, stream>>>(x, wb, out);
}

// Round 5
// 472.391 us; speedup vs baseline: 1.0415x; 1.0415x over previous
//
#include <hip/hip_runtime.h>

// out[B=16384, ONUM=512] = x[B, INUM=4096] @ wB[ONUM, INUM]^T, wB = (u < weight)
// v4 (2nd resubmit — rounds 3+4 were container-level infra failures; kernel
// audited: no OOB, no divergent barrier, vmcnt ledger order-robust):
// 128x128 tile, BK=32, 256 thr (4 waves, 2x2, 64x64/wave, acc4x4 -> 16 MACs/B
// LDS reuse). Deep counted-vmcnt pipeline: B 4-buffered issued 3 tiles ahead,
// A reg-staged 2 tiles ahead; per-step queue = [A(t+2)x4, B(t+3)x2]; step-end
// s_waitcnt vmcnt(8) retires exactly {B(t+1), A(t+1)}. 512 blocks = 2/CU (two
// independent 4-wave barrier domains per CU). XCD-chunked swizzle kept from v2.

#define M_DIM 16384
#define N_DIM 512
#define K_DIM 4096
#define BM 128
#define BN 128
#define BK 32
#define NT (K_DIM / BK)          // 128
#define THREADS 256

using bf16x8 = __attribute__((ext_vector_type(8))) short;
using f32x4  = __attribute__((ext_vector_type(4))) float;

typedef __attribute__((address_space(1))) const void glb_cv;
typedef __attribute__((address_space(3))) void lds_v;

__device__ __forceinline__ unsigned short f2bf(float f) {
    union { float f; unsigned int u; } v;
    v.f = f;
    unsigned int r = v.u + 0x7FFFu + ((v.u >> 16) & 1u);   // RNE
    return (unsigned short)(r >> 16);
}

// ---------------- binarize: wB[o,k] = (u < weight) ? 1.0bf16 : 0 ----------------
__global__ __launch_bounds__(256) void binarize_kernel(const float* __restrict__ w,
                                                       const float* __restrict__ u,
                                                       unsigned short* __restrict__ wb) {
    int i = (blockIdx.x * 256 + threadIdx.x) * 4;
    float4 wv = *(const float4*)(w + i);
    float4 uv = *(const float4*)(u + i);
    ushort4 o;
    o.x = (uv.x < wv.x) ? 0x3F80u : 0u;
    o.y = (uv.y < wv.y) ? 0x3F80u : 0u;
    o.z = (uv.z < wv.z) ? 0x3F80u : 0u;
    o.w = (uv.w < wv.w) ? 0x3F80u : 0u;
    *(ushort4*)(wb + i) = o;
}

// ---------------- GEMM ----------------
__global__ __launch_bounds__(THREADS, 2) void gemm_bin_kernel(const float* __restrict__ x,
                                                              const unsigned short* __restrict__ wb,
                                                              float* __restrict__ out) {
    // A: 2 buffers, padded rows (stride 80 B = 20 banks) — reg-staged ds_write.
    // B: 4 buffers, linear dest for global_load_lds; XOR-swizzled CONTENT:
    //    LDS chunk (row, kc) holds global chunk (row, kc ^ ((row>>1)&3)).
    __shared__ __attribute__((aligned(16))) unsigned short As[2][BM][40];   // 20.5 KB
    __shared__ __attribute__((aligned(16))) unsigned short Bs[4][BN][BK];   // 32 KB

    const int t    = threadIdx.x;
    const int lane = t & 63;
    const int wave = t >> 6;                  // 0..3

    // XCD-chunked swizzle (512 blocks, 512%8==0): bn-sharers of a bm on one XCD.
    const int bid = blockIdx.x;
    const int swz = (bid & 7) * 64 + (bid >> 3);
    const int bn  = swz & 3;
    const int bm  = swz >> 2;

    const int wm  = (wave >> 1) * 64;
    const int wn  = (wave & 1) * 64;
    const int khi = lane >> 4;                // 0..3
    const int l15 = lane & 15;

    f32x4 acc[4][4] = {};

    const float* xg = x + (size_t)(bm * BM) * K_DIM;
    const unsigned short* wbg = wb + (size_t)(bn * BN) * K_DIM;

    float4 sa[4], sb[4];                      // two A reg sets (tile t+1, t+2)

    // A staging: 128x32 fp32 = 1024 float4-chunks; 4/thread. chunk=j*256+t.
#define LOADA(S, k0)                                                             \
    _Pragma("unroll")                                                            \
    for (int j = 0; j < 4; ++j) {                                                \
        int ch = j * 256 + t;                                                    \
        S[j] = *(const float4*)(xg + (size_t)(ch >> 3) * K_DIM + (k0) + (ch & 7) * 4); \
    }

#define STOREA(ab, S)                                                            \
    _Pragma("unroll")                                                            \
    for (int j = 0; j < 4; ++j) {                                                \
        int ch = j * 256 + t;                                                    \
        ushort4 h;                                                               \
        h.x = f2bf(S[j].x); h.y = f2bf(S[j].y);                                  \
        h.z = f2bf(S[j].z); h.w = f2bf(S[j].w);                                  \
        *(ushort4*)(&As[ab][ch >> 3][(ch & 7) * 4]) = h;                         \
    }

    // B staging: 128x32 bf16 = 8 KB = 512 x 16B chunks; 2 gll/thread.
    // Pre-swizzled SOURCE (rule 21): fetch global chunk (rbw, kc ^ ((rbw>>1)&3)).
#define GLLB(b, k0)                                                              \
    _Pragma("unroll")                                                            \
    for (int c = 0; c < 2; ++c) {                                                \
        int e   = c * 256 + t;                                                   \
        int rbw = e >> 2;                                                        \
        int kc  = (e & 3) ^ ((rbw >> 1) & 3);                                    \
        const unsigned short* gsrc = wbg + (size_t)rbw * K_DIM + (k0) + kc * 8;  \
        unsigned short* ldst = (unsigned short*)&Bs[b][0][0] + (size_t)e * 8;    \
        __builtin_amdgcn_global_load_lds((glb_cv*)(const void*)gsrc,             \
                                         (lds_v*)(void*)ldst, 16, 0, 0);         \
    }

#define COMPUTE(ab, bb) {                                                        \
    bf16x8 af[4], bfr[4];                                                        \
    _Pragma("unroll") for (int i = 0; i < 4; ++i)                                \
        af[i] = *(const bf16x8*)(&As[ab][wm + i * 16 + l15][khi * 8]);           \
    _Pragma("unroll") for (int j = 0; j < 4; ++j) {                              \
        int row = wn + j * 16 + l15;                                             \
        int kc  = khi ^ ((row >> 1) & 3);                                        \
        bfr[j] = *(const bf16x8*)(&Bs[bb][row][kc * 8]);                         \
    }                                                                            \
    _Pragma("unroll") for (int i = 0; i < 4; ++i)                                \
        _Pragma("unroll") for (int j = 0; j < 4; ++j)                            \
            acc[i][j] = __builtin_amdgcn_mfma_f32_16x16x32_bf16(af[i], bfr[j],   \
                                                                acc[i][j], 0, 0, 0); \
}

#define ENDSTEP(N)                                                               \
    asm volatile("s_waitcnt vmcnt(" #N ")" ::: "memory");                        \
    /* ds_writes of STOREA follow; "memory" clobber pins them after the wait */

#define BARRIER                                                                  \
    asm volatile("s_waitcnt lgkmcnt(0)" ::: "memory");                           \
    __builtin_amdgcn_s_barrier();                                                \
    __builtin_amdgcn_sched_barrier(0);

    // Step t: LOADA(tile t+2) -> GLLB(tile t+3) -> COMPUTE(t) -> vmcnt(8)
    //         -> STOREA(tile t+1) -> barrier.
    // Queue entering step t: [B(t+1)x2, A(t+1)x4, B(t+2)x2] (8 outstanding);
    // after issues: 14; vmcnt(8) retires exactly B(t+1)+A(t+1).
    // Robust to intra-step issue reordering: B(t)'s glls are older than the
    // 12 ops issued in steps t-2,t-1; vmcnt(8) leaves <=8 outstanding, all
    // among those 12 youngest -> B(t) always retired before step t computes.
#define STEP(abc, abn, bbc, bbp, LD, ST)                                         \
    LOADA(LD, kpa); kpa += BK;                                                   \
    GLLB(bbp, kpb); kpb += BK;                                                   \
    COMPUTE(abc, bbc);                                                           \
    ENDSTEP(8);                                                                  \
    STOREA(abn, ST);                                                             \
    BARRIER;

    // ---- prologue: establish invariant for t=0 ----
    GLLB(0, 0);                    // B(0)
    LOADA(sa, 0);                  // A(0)
    asm volatile("s_waitcnt vmcnt(0)" ::: "memory");
    STOREA(0, sa);                 // tile0 -> As[0]
    GLLB(1, BK);                   // B(1)   } queue order must be
    LOADA(sb, BK);                 // A(1)   } [B1, A1, B2]
    GLLB(2, 2 * BK);               // B(2)   }
    BARRIER;

    int kpa = 2 * BK;              // next A tile to load
    int kpb = 3 * BK;              // next B tile to issue

    // ---- main loop: t = 0..123, unrolled x4 ----
    for (int it = 0; it < 31; ++it) {
        STEP(0, 1, 0, 3, sa, sb)   // t%4==0
        STEP(1, 0, 1, 0, sb, sa)   // t%4==1
        STEP(0, 1, 2, 1, sa, sb)   // t%4==2
        STEP(1, 0, 3, 2, sb, sa)   // t%4==3
    }
    // ---- t=124: full step ----
    STEP(0, 1, 0, 3, sa, sb)
    // ---- t=125: last A load (tile 127), no B issue ----
    LOADA(sb, kpa);
    COMPUTE(1, 1);
    ENDSTEP(6);                    // retires B(126)+A(126); leaves B(127),A(127)
    STOREA(0, sa);
    BARRIER;
    // ---- t=126: no issues; drain for A(127) ----
    COMPUTE(0, 2);
    ENDSTEP(0);
    STOREA(1, sb);
    BARRIER;
    // ---- t=127: compute only ----
    COMPUTE(1, 3);

    // ---- epilogue: C/D layout col=lane&15, row=(lane>>4)*4+reg ----
    const int col0 = bn * BN + wn + l15;
    const int row0 = bm * BM + wm + khi * 4;
#pragma unroll
    for (int i = 0; i < 4; ++i)
#pragma unroll
        for (int j = 0; j < 4; ++j)
#pragma unroll
            for (int r = 0; r < 4; ++r)
                out[(size_t)(row0 + i * 16 + r) * N_DIM + (col0 + j * 16)] = acc[i][j][r];
}

extern "C" void kernel_launch(void* const* d_in, const int* in_sizes, int n_in,
                              void* d_out, int out_size, void* d_ws, size_t ws_size,
                              hipStream_t stream) {
    const float* x = (const float*)d_in[0];
    const float* w = (const float*)d_in[1];
    const float* u = (const float*)d_in[2];
    float* out = (float*)d_out;
    unsigned short* wb = (unsigned short*)d_ws;   // 512*4096*2 = 4 MB

    binarize_kernel<<<dim3(N_DIM * K_DIM / 4 / 256), dim3(256), 0, stream>>>(w, u, wb);

    gemm_bin_kernel<<<dim3((N_DIM / BN) * (M_DIM / BM)), dim3(THREADS), 0, stream>>>(x, wb, out);
}